// Round 3
// baseline (525.803 us; speedup 1.0000x reference)
//
#include <hip/hip_runtime.h>

// int4 grouped-quant GEMM: out[64][28672] = x[64][8192] . W^T + bias
// W packed [N][K/2] int32, one byte/int32 = 2 nibbles (low = even k), zp = 8,
// per-128-k scales. Reference dtype fp16 -> harness promotes x/scales/bias/out
// to FP32 (only bf16 stays 16-bit). Memory-bound on the 470 MB weight stream
// (~75 us @ 6.3 TB/s achievable).

typedef __attribute__((ext_vector_type(8))) short short8;  // MFMA bf16 A/B frag (4 VGPR)
typedef __attribute__((ext_vector_type(4))) float f32x4;   // MFMA C/D frag
typedef __attribute__((ext_vector_type(4))) int   i32x4;

struct WGrp { i32x4 w0, w1, w2, w3; float s; };  // one 128-k weight group, one lane's share

// fp32 -> bf16 bits via HW v_cvt (compiler pairs these into v_cvt_pk_bf16_f32)
static __device__ __forceinline__ short bf(float f) {
    return __builtin_bit_cast(short, (__bf16)f);
}

// Load one 128-k weight group (16 int32/lane, nontemporal: don't pollute L1) + scale.
static __device__ __forceinline__ WGrp load_grp(const int* __restrict__ wrow,
                                                const float* __restrict__ srow, int g) {
    WGrp r;
    const i32x4* p = (const i32x4*)(wrow + g * 64);   // 16B-aligned (quad*4 ints)
    r.w0 = __builtin_nontemporal_load(p);
    r.w1 = __builtin_nontemporal_load(p + 4);
    r.w2 = __builtin_nontemporal_load(p + 8);
    r.w3 = __builtin_nontemporal_load(p + 12);
    r.s  = srow[g];
    return r;
}

// A-fragment: 8 consecutive fp32 of one x row -> bf16 frag.
static __device__ __forceinline__ short8 loadA(const float* __restrict__ p) {
    f32x4 lo = *(const f32x4*)p;
    f32x4 hi = *(const f32x4*)(p + 4);
    short8 r = { bf(lo[0]), bf(lo[1]), bf(lo[2]), bf(lo[3]),
                 bf(hi[0]), bf(hi[1]), bf(hi[2]), bf(hi[3]) };
    return r;
}

// One 32-k MFMA step for all 4 m-tiles. w = this lane's 4 packed int32.
static __device__ __forceinline__ void kstep(const i32x4& w, float s,
                                             const float* __restrict__ xp, int K,
                                             f32x4& a0, f32x4& a1, f32x4& a2, f32x4& a3) {
    short8 b;
    #pragma unroll
    for (int t = 0; t < 4; ++t) {
        int v = w[t];
        b[2 * t]     = bf(((float)(v & 0xF)        - 8.0f) * s);  // even k
        b[2 * t + 1] = bf(((float)((v >> 4) & 0xF) - 8.0f) * s);  // odd k
    }
    a0 = __builtin_amdgcn_mfma_f32_16x16x32_bf16(loadA(xp),                  b, a0, 0, 0, 0);
    a1 = __builtin_amdgcn_mfma_f32_16x16x32_bf16(loadA(xp + 16 * (size_t)K), b, a1, 0, 0, 0);
    a2 = __builtin_amdgcn_mfma_f32_16x16x32_bf16(loadA(xp + 32 * (size_t)K), b, a2, 0, 0, 0);
    a3 = __builtin_amdgcn_mfma_f32_16x16x32_bf16(loadA(xp + 48 * (size_t)K), b, a3, 0, 0, 0);
}

static __device__ __forceinline__ void compute_grp(const WGrp& p, int g,
                                                   const float* __restrict__ xq, int K,
                                                   f32x4& a0, f32x4& a1, f32x4& a2, f32x4& a3) {
    const float* xp = xq + (size_t)g * 128;
    kstep(p.w0, p.s, xp,      K, a0, a1, a2, a3);
    kstep(p.w1, p.s, xp + 32, K, a0, a1, a2, a3);
    kstep(p.w2, p.s, xp + 64, K, a0, a1, a2, a3);
    kstep(p.w3, p.s, xp + 96, K, a0, a1, a2, a3);
}

__global__ __launch_bounds__(256)
void int4mm_kernel(const float* __restrict__ x,     // [64][K] fp32
                   const int*   __restrict__ wp,    // [N][K/2]
                   const float* __restrict__ sc,    // [N][K/128] fp32
                   const float* __restrict__ bias,  // [N] fp32
                   float*       __restrict__ out,   // [64][N] fp32
                   int K, int N)
{
    const int lane = threadIdx.x & 63;
    const int wave = threadIdx.x >> 6;
    const int quad = lane >> 4;                  // k-quarter within a 32-k MFMA step
    const int l15  = lane & 15;
    const int n    = (blockIdx.x * 4 + wave) * 16 + l15;   // this lane's N column
    const int Kh   = K >> 1;
    const int ng   = K / 128;                    // 64 groups (ng % 4 == 0, ng >= 8)

    const int*   wrow = wp + (size_t)n * Kh + quad * 4;
    const float* srow = sc + (size_t)n * ng;
    const float* xq   = x + (size_t)l15 * K + quad * 8;

    f32x4 acc0 = {0.f, 0.f, 0.f, 0.f};
    f32x4 acc1 = {0.f, 0.f, 0.f, 0.f};
    f32x4 acc2 = {0.f, 0.f, 0.f, 0.f};
    f32x4 acc3 = {0.f, 0.f, 0.f, 0.f};

    // Depth-2 register pipeline over 128-k weight groups, 4 named buffers (rule #20:
    // no runtime indexing): loads for g+2..g+5 issue before computes consume g..g+3.
    WGrp p0 = load_grp(wrow, srow, 0);
    WGrp p1 = load_grp(wrow, srow, 1);

    #pragma unroll 1
    for (int g = 0; g < ng - 4; g += 4) {
        WGrp n0 = load_grp(wrow, srow, g + 2);
        WGrp n1 = load_grp(wrow, srow, g + 3);
        compute_grp(p0, g,     xq, K, acc0, acc1, acc2, acc3);
        compute_grp(p1, g + 1, xq, K, acc0, acc1, acc2, acc3);
        p0 = load_grp(wrow, srow, g + 4);
        p1 = load_grp(wrow, srow, g + 5);
        compute_grp(n0, g + 2, xq, K, acc0, acc1, acc2, acc3);
        compute_grp(n1, g + 3, xq, K, acc0, acc1, acc2, acc3);
    }
    {   // tail: groups ng-4 .. ng-1 (p0/p1 hold ng-4, ng-3)
        WGrp n0 = load_grp(wrow, srow, ng - 2);
        WGrp n1 = load_grp(wrow, srow, ng - 1);
        compute_grp(p0, ng - 4, xq, K, acc0, acc1, acc2, acc3);
        compute_grp(p1, ng - 3, xq, K, acc0, acc1, acc2, acc3);
        compute_grp(n0, ng - 2, xq, K, acc0, acc1, acc2, acc3);
        compute_grp(n1, ng - 1, xq, K, acc0, acc1, acc2, acc3);
    }

    // Epilogue. C/D layout (m89-verified): col = lane&15 (= n), row = quad*4 + reg.
    const float bv = bias[n];
    float* orow = out + (size_t)(quad * 4) * N + n;
    #pragma unroll
    for (int r = 0; r < 4; ++r) {
        orow[(size_t)(r)      * N] = acc0[r] + bv;
        orow[(size_t)(r + 16) * N] = acc1[r] + bv;
        orow[(size_t)(r + 32) * N] = acc2[r] + bv;
        orow[(size_t)(r + 48) * N] = acc3[r] + bv;
    }
}

extern "C" void kernel_launch(void* const* d_in, const int* in_sizes, int n_in,
                              void* d_out, int out_size, void* d_ws, size_t ws_size,
                              hipStream_t stream)
{
    const float* x    = (const float*)d_in[0];
    const int*   wp   = (const int*)d_in[1];
    const float* sc   = (const float*)d_in[2];
    const float* bias = (const float*)d_in[3];
    float*       out  = (float*)d_out;

    const int N  = in_sizes[3];                       // 28672
    const long long Kh = (long long)in_sizes[1] / N;  // 4096
    const int K  = (int)(2 * Kh);                     // 8192

    // 448 WGs x 4 waves; each wave: 16 N-cols x 64 M-rows x full K.
    const int wgs = N / 64;
    int4mm_kernel<<<wgs, 256, 0, stream>>>(x, wp, sc, bias, out, K, N);
}

// Round 4
// 168.187 us; speedup vs baseline: 3.1263x; 3.1263x over previous
//
#include <hip/hip_runtime.h>
#include <stdint.h>

// int4 grouped-quant GEMM: out[64][28672] = x[64][8192] . W^T + bias
// W packed [N][K/2] int32, one byte/int32 = 2 nibbles (low = even k), zp = 8,
// per-128-k scales. fp16 ref -> harness gives x/scales/bias/out as FP32.
// HBM-bound on the 470 MB weight stream (~75 us @ 6.3 TB/s achievable).
// Round-4 fix: x is pre-packed (xpack) into MFMA A-fragment order as bf16 in
// d_ws, staged per-128-k-group into LDS (global_load_lds, lane-linear ->
// conflict-free ds_read_b128), shared by all 4 waves of the WG.

typedef __attribute__((ext_vector_type(8))) short short8;  // MFMA bf16 A/B frag
typedef __attribute__((ext_vector_type(4))) float f32x4;   // MFMA C/D frag
typedef __attribute__((ext_vector_type(4))) int   i32x4;

struct WGrp { i32x4 w0, w1, w2, w3; float s; };  // one 128-k weight group / lane

static __device__ __forceinline__ short bf(float f) {
    return __builtin_bit_cast(short, (__bf16)f);   // HW v_cvt, RNE
}

// async global->LDS, 16 B per lane. LDS dest = wave-uniform base + lane*16 (HW).
static __device__ __forceinline__ void gload_lds16(const void* gp, void* lp) {
    __builtin_amdgcn_global_load_lds(
        (const __attribute__((address_space(1))) unsigned int*)gp,
        (__attribute__((address_space(3))) unsigned int*)lp, 16, 0, 0);
}

// One 128-k weight group: 16 int32/lane, nontemporal (streamed once).
static __device__ __forceinline__ WGrp load_grp(const int* __restrict__ wrow,
                                                const float* __restrict__ srow, int g) {
    WGrp r;
    const i32x4* p = (const i32x4*)(wrow + g * 64);
    r.w0 = __builtin_nontemporal_load(p);
    r.w1 = __builtin_nontemporal_load(p + 4);
    r.w2 = __builtin_nontemporal_load(p + 8);
    r.w3 = __builtin_nontemporal_load(p + 12);
    r.s  = srow[g];
    return r;
}

// One 32-k MFMA step, 4 m-tiles. A-frags from LDS at ab + mt*1024 + lane*16.
static __device__ __forceinline__ void kstep(const i32x4& w, float s,
                                             const char* ab, int lane,
                                             f32x4& a0, f32x4& a1, f32x4& a2, f32x4& a3) {
    short8 b;
    #pragma unroll
    for (int t = 0; t < 4; ++t) {
        int v = w[t];
        b[2 * t]     = bf(((float)(v & 0xF)        - 8.0f) * s);  // even k
        b[2 * t + 1] = bf(((float)((v >> 4) & 0xF) - 8.0f) * s);  // odd k
    }
    short8 x0 = *(const short8*)(ab +    0 + lane * 16);
    short8 x1 = *(const short8*)(ab + 1024 + lane * 16);
    short8 x2 = *(const short8*)(ab + 2048 + lane * 16);
    short8 x3 = *(const short8*)(ab + 3072 + lane * 16);
    a0 = __builtin_amdgcn_mfma_f32_16x16x32_bf16(x0, b, a0, 0, 0, 0);
    a1 = __builtin_amdgcn_mfma_f32_16x16x32_bf16(x1, b, a1, 0, 0, 0);
    a2 = __builtin_amdgcn_mfma_f32_16x16x32_bf16(x2, b, a2, 0, 0, 0);
    a3 = __builtin_amdgcn_mfma_f32_16x16x32_bf16(x3, b, a3, 0, 0, 0);
}

static __device__ __forceinline__ void compute_grp(const WGrp& p, const char* buf, int lane,
                                                   f32x4& a0, f32x4& a1, f32x4& a2, f32x4& a3) {
    kstep(p.w0, p.s, buf,         lane, a0, a1, a2, a3);
    kstep(p.w1, p.s, buf +  4096, lane, a0, a1, a2, a3);
    kstep(p.w2, p.s, buf +  8192, lane, a0, a1, a2, a3);
    kstep(p.w3, p.s, buf + 12288, lane, a0, a1, a2, a3);
}

// Stage group g (16 KB frag-ordered bf16) into LDS buffer. Wave w copies 4 KB.
static __device__ __forceinline__ void stage_grp(const unsigned short* __restrict__ xf,
                                                 int g, char* buf, int wave, int lane) {
    const char* src = (const char*)xf + (size_t)g * 16384 + wave * 4096 + lane * 16;
    char* dst = buf + wave * 4096;                 // wave-uniform; HW adds lane*16
    #pragma unroll
    for (int j = 0; j < 4; ++j)
        gload_lds16(src + j * 1024, dst + j * 1024);
}

// x fp32 [64][K] -> bf16 in A-fragment order: xf[g][st][mt][lane][8]
__global__ __launch_bounds__(256)
void xpack_kernel(const float* __restrict__ x, unsigned short* __restrict__ xf, int K) {
    int c    = blockIdx.x * 256 + threadIdx.x;     // one 16 B chunk per thread
    int g    = c >> 10;
    int st   = (c >> 8) & 3;
    int mt   = (c >> 6) & 3;
    int lane = c & 63;
    int quad = lane >> 4, l15 = lane & 15;
    const float* p = x + (size_t)(l15 + mt * 16) * K + g * 128 + st * 32 + quad * 8;
    f32x4 lo = *(const f32x4*)p;
    f32x4 hi = *(const f32x4*)(p + 4);
    short8 r = { bf(lo[0]), bf(lo[1]), bf(lo[2]), bf(lo[3]),
                 bf(hi[0]), bf(hi[1]), bf(hi[2]), bf(hi[3]) };
    *(short8*)(xf + (size_t)c * 8) = r;
}

__global__ __launch_bounds__(256)
void int4mm_kernel(const unsigned short* __restrict__ xf,  // bf16 frag-ordered x
                   const int*   __restrict__ wp,           // [N][K/2]
                   const float* __restrict__ sc,           // [N][K/128]
                   const float* __restrict__ bias,         // [N]
                   float*       __restrict__ out,          // [64][N]
                   int K, int N)
{
    __shared__ i32x4 ldsq[2048];                   // 2 x 16 KB double buffer
    char* lds = (char*)ldsq;

    const int lane = threadIdx.x & 63;
    const int wave = threadIdx.x >> 6;
    const int quad = lane >> 4;
    const int l15  = lane & 15;
    const int n    = (blockIdx.x * 4 + wave) * 16 + l15;   // this lane's N column
    const int Kh   = K >> 1;
    const int ng   = K / 128;                      // 64 groups

    const int*   wrow = wp + (size_t)n * Kh + quad * 4;
    const float* srow = sc + (size_t)n * ng;

    f32x4 acc0 = {0.f, 0.f, 0.f, 0.f};
    f32x4 acc1 = {0.f, 0.f, 0.f, 0.f};
    f32x4 acc2 = {0.f, 0.f, 0.f, 0.f};
    f32x4 acc3 = {0.f, 0.f, 0.f, 0.f};

    // Weight register pipeline: 4 named group buffers, reloaded 4 groups ahead.
    WGrp p0 = load_grp(wrow, srow, 0);
    WGrp p1 = load_grp(wrow, srow, 1);
    WGrp p2 = load_grp(wrow, srow, 2);
    WGrp p3 = load_grp(wrow, srow, 3);
    stage_grp(xf, 0, lds, wave, lane);
    __syncthreads();

    // Per sub-iteration: issue next weight loads + next x stage FIRST (their
    // latency overlaps this group's compute; the barrier's vmcnt(0) drain then
    // has ~a full compute-group of cover), then compute, then barrier.
    #pragma unroll 1
    for (int g = 0; g < ng; g += 4) {
        const int c4 = (g + 4 < ng) ? g + 4 : ng - 1;   // clamped tail reloads
        const int c5 = (g + 5 < ng) ? g + 5 : ng - 1;   // (redundant, in-bounds,
        const int c6 = (g + 6 < ng) ? g + 6 : ng - 1;   //  written to dead bufs)
        const int c7 = (g + 7 < ng) ? g + 7 : ng - 1;
        {
            WGrp t = load_grp(wrow, srow, c4);
            stage_grp(xf, (g + 1 < ng) ? g + 1 : ng - 1, lds + 16384, wave, lane);
            compute_grp(p0, lds, lane, acc0, acc1, acc2, acc3);
            p0 = t;
            __syncthreads();
        }
        {
            WGrp t = load_grp(wrow, srow, c5);
            stage_grp(xf, g + 2, lds, wave, lane);          // g+2 <= ng-2
            compute_grp(p1, lds + 16384, lane, acc0, acc1, acc2, acc3);
            p1 = t;
            __syncthreads();
        }
        {
            WGrp t = load_grp(wrow, srow, c6);
            stage_grp(xf, g + 3, lds + 16384, wave, lane);  // g+3 <= ng-1
            compute_grp(p2, lds, lane, acc0, acc1, acc2, acc3);
            p2 = t;
            __syncthreads();
        }
        {
            WGrp t = load_grp(wrow, srow, c7);
            stage_grp(xf, c4, lds, wave, lane);
            compute_grp(p3, lds + 16384, lane, acc0, acc1, acc2, acc3);
            p3 = t;
            __syncthreads();
        }
    }

    // Epilogue. C/D layout (m89-verified): col = lane&15 (= n), row = quad*4 + reg.
    const float bv = bias[n];
    float* orow = out + (size_t)(quad * 4) * N + n;
    #pragma unroll
    for (int r = 0; r < 4; ++r) {
        orow[(size_t)(r)      * N] = acc0[r] + bv;
        orow[(size_t)(r + 16) * N] = acc1[r] + bv;
        orow[(size_t)(r + 32) * N] = acc2[r] + bv;
        orow[(size_t)(r + 48) * N] = acc3[r] + bv;
    }
}

extern "C" void kernel_launch(void* const* d_in, const int* in_sizes, int n_in,
                              void* d_out, int out_size, void* d_ws, size_t ws_size,
                              hipStream_t stream)
{
    const float* x    = (const float*)d_in[0];
    const int*   wp   = (const int*)d_in[1];
    const float* sc   = (const float*)d_in[2];
    const float* bias = (const float*)d_in[3];
    float*       out  = (float*)d_out;

    const int N  = in_sizes[3];                       // 28672
    const long long Kh = (long long)in_sizes[1] / N;  // 4096
    const int K  = (int)(2 * Kh);                     // 8192

    unsigned short* xf = (unsigned short*)d_ws;       // 1 MB frag-ordered bf16 x

    const int chunks = (K / 128) * 1024;              // 65536 x 16 B = 1 MB
    xpack_kernel<<<chunks / 256, 256, 0, stream>>>(x, xf, K);
    int4mm_kernel<<<N / 64, 256, 0, stream>>>(xf, wp, sc, bias, out, K, N);
}